// Round 1
// baseline (1409.898 us; speedup 1.0000x reference)
//
#include <hip/hip_runtime.h>
#include <cstdint>
#include <cstddef>

#define B_    16
#define N_    170
#define T_    64
#define NT_   (N_ * T_)      /* 10880 tokens per batch */
#define C_    512
#define KH_   8

typedef unsigned short u16;
typedef float  f32x4  __attribute__((ext_vector_type(4)));
typedef short  bf16x8 __attribute__((ext_vector_type(8)));

__device__ __forceinline__ u16 f2bf(float f) {
  union { float f; unsigned u; } v; v.f = f;
  unsigned r = v.u + 0x7fffu + ((v.u >> 16) & 1u);   // RNE
  return (u16)(r >> 16);
}

#define GLDS16(g, l) \
  __builtin_amdgcn_global_load_lds((const __attribute__((address_space(1))) void*)(g), \
                                   (__attribute__((address_space(3))) void*)(l), 16, 0, 0)

// ---------------------------------------------------------------------------
// Weight fp32 -> bf16 (layout preserved: [o][c], c contiguous)
// ---------------------------------------------------------------------------
__global__ __launch_bounds__(256) void wconv(const float* __restrict__ wq, const float* __restrict__ wk,
                                             const float* __restrict__ wv, const float* __restrict__ wo,
                                             u16* __restrict__ oq, u16* __restrict__ ok,
                                             u16* __restrict__ ov, u16* __restrict__ oo) {
  int idx = blockIdx.x * 256 + threadIdx.x;        // 262144 threads, 4 floats each
  int mat = idx >> 16;
  int off = (idx & 65535) * 4;
  const float* s = (mat == 0) ? wq : (mat == 1) ? wk : (mat == 2) ? wv : wo;
  u16* d = (mat == 0) ? oq : (mat == 1) ? ok : (mat == 2) ? ov : oo;
  float4 v = *(const float4*)(s + off);
  u16 o[4] = { f2bf(v.x), f2bf(v.y), f2bf(v.z), f2bf(v.w) };
  *(uint2*)(d + off) = *(uint2*)o;
}

// ---------------------------------------------------------------------------
// concat(x, tem) on channel dim + transpose to token-major bf16:
// xin_tm[b][nt][c] (c contiguous). 64x64 tile per block via LDS.
// ---------------------------------------------------------------------------
__global__ __launch_bounds__(256) void concat_tr(const float* __restrict__ x,
                                                 const float* __restrict__ tem,
                                                 u16* __restrict__ xin_tm) {
  __shared__ u16 tile[64 * 72];
  int mt = blockIdx.x, ct = blockIdx.y, b = blockIdx.z;
  const float* src = (ct < 4) ? (x   + ((size_t)b * 256 + (size_t)ct * 64) * NT_)
                              : (tem + ((size_t)b * 256 + (size_t)(ct - 4) * 64) * NT_);
  int m0 = mt * 64;
  int tid = threadIdx.x;
  // read 64 channel-rows x 64 tokens (coalesced float4), cast, stash [c][m]
  for (int g = tid; g < 1024; g += 256) {
    int row = g >> 4, part = (g & 15) * 4;
    float4 v = *(const float4*)(src + (size_t)row * NT_ + m0 + part);
    u16* t = &tile[row * 72 + part];
    t[0] = f2bf(v.x); t[1] = f2bf(v.y); t[2] = f2bf(v.z); t[3] = f2bf(v.w);
  }
  __syncthreads();
  // write token rows (coalesced 16B)
  for (int h = tid; h < 512; h += 256) {
    int mm = h >> 3, part = (h & 7) * 8;
    u16 vals[8];
#pragma unroll
    for (int e = 0; e < 8; e++) vals[e] = tile[(part + e) * 72 + mm];
    *(uint4*)(xin_tm + ((size_t)(b * NT_ + m0 + mm)) * 512 + ct * 64 + part) = *(uint4*)vals;
  }
}

// ---------------------------------------------------------------------------
// C[M][N] = sum_k A[m][k]*B[n][k]  (both operands K-contiguous, bf16)
// MODE 0: bf16 out, bias indexed by col (token-major q/k)
// MODE 1: bf16 out, bias indexed by row (channel-major v)
// MODE 2: f32 out + relu, bias indexed by row (final y)
// 128x128 tile, BK=32, 4 waves, 16x16x32 MFMA, global_load_lds staging.
// ---------------------------------------------------------------------------
template <int MODE>
__global__ __launch_bounds__(256) void gemm_bt(
    const u16* __restrict__ A, int lda, size_t aBatch,
    const u16* __restrict__ Bm, int ldb, size_t bBatch,
    void* __restrict__ Cv, int ldc, size_t cBatch,
    const float* __restrict__ bias, int K) {
  __shared__ u16 As[128 * 32];
  __shared__ u16 Bs[128 * 32];
  int b = blockIdx.z;
  const u16* Ab = A + (size_t)b * aBatch;
  const u16* Bb = Bm + (size_t)b * bBatch;
  int tid = threadIdx.x;
  int lane = tid & 63, w = tid >> 6;
  int quad = lane >> 4, l15 = lane & 15;
  int rowA0 = blockIdx.y * 128;
  int rowB0 = blockIdx.x * 128;
  int wr = (w >> 1) * 64, wc = (w & 1) * 64;

  f32x4 acc[4][4];
#pragma unroll
  for (int i = 0; i < 4; i++)
#pragma unroll
    for (int j = 0; j < 4; j++) acc[i][j] = (f32x4){0.f, 0.f, 0.f, 0.f};

  for (int k0 = 0; k0 < K; k0 += 32) {
#pragma unroll
    for (int r = 0; r < 2; r++) {
      int chunk = tid + r * 256;             // 512 x 16B chunks per tile
      int row = chunk >> 2, kk = (chunk & 3) * 8;
      const u16* ga = Ab + (size_t)(rowA0 + row) * lda + k0 + kk;
      GLDS16(ga, &As[(r * 256 + w * 64) * 8]);   // wave-uniform LDS base + lane*16
      const u16* gb = Bb + (size_t)(rowB0 + row) * ldb + k0 + kk;
      GLDS16(gb, &Bs[(r * 256 + w * 64) * 8]);
    }
    __syncthreads();
    bf16x8 af[4], bfr[4];
#pragma unroll
    for (int i = 0; i < 4; i++) af[i]  = *(const bf16x8*)&As[(wr + i * 16 + l15) * 32 + quad * 8];
#pragma unroll
    for (int j = 0; j < 4; j++) bfr[j] = *(const bf16x8*)&Bs[(wc + j * 16 + l15) * 32 + quad * 8];
#pragma unroll
    for (int i = 0; i < 4; i++)
#pragma unroll
      for (int j = 0; j < 4; j++)
        acc[i][j] = __builtin_amdgcn_mfma_f32_16x16x32_bf16(af[i], bfr[j], acc[i][j], 0, 0, 0);
    __syncthreads();
  }

  int gr0 = rowA0 + wr, gc0 = rowB0 + wc;
  if (MODE == 0) {
    u16* C = (u16*)Cv + (size_t)b * cBatch;
#pragma unroll
    for (int j = 0; j < 4; j++) {
      int Cc = gc0 + j * 16 + l15;
      float bj = bias[Cc];
#pragma unroll
      for (int i = 0; i < 4; i++)
#pragma unroll
        for (int r = 0; r < 4; r++) {
          int R = gr0 + i * 16 + quad * 4 + r;
          C[(size_t)R * ldc + Cc] = f2bf(acc[i][j][r] + bj);
        }
    }
  } else if (MODE == 1) {
    u16* C = (u16*)Cv + (size_t)b * cBatch;
#pragma unroll
    for (int i = 0; i < 4; i++)
#pragma unroll
      for (int r = 0; r < 4; r++) {
        int R = gr0 + i * 16 + quad * 4 + r;
        float br = bias[R];
#pragma unroll
        for (int j = 0; j < 4; j++)
          C[(size_t)R * ldc + gc0 + j * 16 + l15] = f2bf(acc[i][j][r] + br);
      }
  } else {
    float* C = (float*)Cv + (size_t)b * cBatch;
#pragma unroll
    for (int i = 0; i < 4; i++)
#pragma unroll
      for (int r = 0; r < 4; r++) {
        int R = gr0 + i * 16 + quad * 4 + r;
        float br = bias[R];
#pragma unroll
        for (int j = 0; j < 4; j++) {
          float v = acc[i][j][r] + br;
          C[(size_t)R * ldc + gc0 + j * 16 + l15] = fmaxf(v, 0.f);
        }
      }
  }
}

// ---------------------------------------------------------------------------
// Causal attention per (head, b, n): S=QK^T/8, mask, softmax, O=PV.
// q/k token-major [t][d] (d contig); v channel-major => V^T [d][s] (s contig).
// Output token-major bf16 to ao_tm.
// ---------------------------------------------------------------------------
__global__ __launch_bounds__(256) void attn(const u16* __restrict__ q_tm,
                                            const u16* __restrict__ k_tm,
                                            const u16* __restrict__ v_cm,
                                            u16* __restrict__ ao_tm) {
  __shared__ u16 qsh[64 * 72], ksh[64 * 72], vsh[64 * 72], psh[64 * 72];
  int n = blockIdx.x, kh = blockIdx.y, b = blockIdx.z;
  int tid = threadIdx.x, lane = tid & 63, w = tid >> 6;
  int quad = lane >> 4, l15 = lane & 15;

  const u16* qbase = q_tm + ((size_t)(b * NT_ + n * 64)) * 512 + kh * 64;
  const u16* kbase = k_tm + ((size_t)(b * NT_ + n * 64)) * 512 + kh * 64;
  const u16* vbase = v_cm + ((size_t)(b * 512 + kh * 64)) * NT_ + n * 64;

  for (int g = tid; g < 512; g += 256) {
    int row = g >> 3, part = (g & 7) * 8;
    *(uint4*)&qsh[row * 72 + part] = *(const uint4*)(qbase + (size_t)row * 512 + part);
    *(uint4*)&ksh[row * 72 + part] = *(const uint4*)(kbase + (size_t)row * 512 + part);
    *(uint4*)&vsh[row * 72 + part] = *(const uint4*)(vbase + (size_t)row * NT_ + part);
  }
  __syncthreads();

  // S rows [16w, 16w+16)
  f32x4 sacc[4];
#pragma unroll
  for (int j = 0; j < 4; j++) sacc[j] = (f32x4){0.f, 0.f, 0.f, 0.f};
  bf16x8 aq[2];
#pragma unroll
  for (int kc = 0; kc < 2; kc++)
    aq[kc] = *(const bf16x8*)&qsh[(w * 16 + l15) * 72 + kc * 32 + quad * 8];
#pragma unroll
  for (int j = 0; j < 4; j++)
#pragma unroll
    for (int kc = 0; kc < 2; kc++) {
      bf16x8 bk = *(const bf16x8*)&ksh[(j * 16 + l15) * 72 + kc * 32 + quad * 8];
      sacc[j] = __builtin_amdgcn_mfma_f32_16x16x32_bf16(aq[kc], bk, sacc[j], 0, 0, 0);
    }

  // mask + softmax; row t = 16w + quad*4 + r, col s = 16j + l15
  float pv[4][4];
#pragma unroll
  for (int r = 0; r < 4; r++) {
    int t = w * 16 + quad * 4 + r;
    float m = -3.4e38f;
#pragma unroll
    for (int j = 0; j < 4; j++) {
      int s = j * 16 + l15;
      float v = sacc[j][r] * 0.125f;
      if (s > t) v = -32767.0f;
      pv[j][r] = v;
      m = fmaxf(m, v);
    }
#pragma unroll
    for (int off = 1; off < 16; off <<= 1) m = fmaxf(m, __shfl_xor(m, off, 16));
    float sum = 0.f;
#pragma unroll
    for (int j = 0; j < 4; j++) {
      float e = __expf(pv[j][r] - m);
      pv[j][r] = e;
      sum += e;
    }
#pragma unroll
    for (int off = 1; off < 16; off <<= 1) sum += __shfl_xor(sum, off, 16);
    float inv = 1.f / sum;
#pragma unroll
    for (int j = 0; j < 4; j++)
      psh[(size_t)t * 72 + j * 16 + l15] = f2bf(pv[j][r] * inv);
  }
  // PV: same wave reads only its own 16 rows of psh -> no barrier needed
  f32x4 oacc[4];
#pragma unroll
  for (int j = 0; j < 4; j++) oacc[j] = (f32x4){0.f, 0.f, 0.f, 0.f};
  bf16x8 ap[2];
#pragma unroll
  for (int kc = 0; kc < 2; kc++)
    ap[kc] = *(const bf16x8*)&psh[(w * 16 + l15) * 72 + kc * 32 + quad * 8];
#pragma unroll
  for (int dj = 0; dj < 4; dj++)
#pragma unroll
    for (int kc = 0; kc < 2; kc++) {
      bf16x8 bv = *(const bf16x8*)&vsh[(dj * 16 + l15) * 72 + kc * 32 + quad * 8];
      oacc[dj] = __builtin_amdgcn_mfma_f32_16x16x32_bf16(ap[kc], bv, oacc[dj], 0, 0, 0);
    }

  u16* ob = ao_tm + ((size_t)(b * NT_ + n * 64)) * 512 + kh * 64;
#pragma unroll
  for (int dj = 0; dj < 4; dj++)
#pragma unroll
    for (int r = 0; r < 4; r++) {
      int t = w * 16 + quad * 4 + r, d = dj * 16 + l15;
      ob[(size_t)t * 512 + d] = f2bf(oacc[dj][r]);
    }
}

// ---------------------------------------------------------------------------
extern "C" void kernel_launch(void* const* d_in, const int* in_sizes, int n_in,
                              void* d_out, int out_size, void* d_ws, size_t ws_size,
                              hipStream_t stream) {
  const float* x   = (const float*)d_in[0];
  const float* tem = (const float*)d_in[1];
  const float* Wq  = (const float*)d_in[2];
  const float* bq  = (const float*)d_in[3];
  const float* Wk  = (const float*)d_in[4];
  const float* bk  = (const float*)d_in[5];
  const float* Wv  = (const float*)d_in[6];
  const float* bv  = (const float*)d_in[7];
  const float* Wo  = (const float*)d_in[8];
  const float* bo  = (const float*)d_in[9];
  float* out = (float*)d_out;

  const size_t E = (size_t)B_ * 512 * NT_;   // 89,128,960 elems per bf16 tensor
  u16* xin_tm = (u16*)d_ws;                  // [b][nt][512]; later reused as ao_tm
  u16* q_tm   = xin_tm + E;                  // [b][nt][512]
  u16* k_tm   = q_tm + E;                    // [b][nt][512]
  u16* v_cm   = k_tm + E;                    // [b][512][nt]
  u16* wqb    = v_cm + E;
  u16* wkb    = wqb + 262144;
  u16* wvb    = wkb + 262144;
  u16* wob    = wvb + 262144;
  u16* ao_tm  = xin_tm;                      // alias: xin dead after QKV GEMMs

  const size_t sBNT = (size_t)NT_ * 512;     // per-batch stride (both layouts)

  wconv<<<1024, 256, 0, stream>>>(Wq, Wk, Wv, Wo, wqb, wkb, wvb, wob);
  concat_tr<<<dim3(N_, 8, B_), 256, 0, stream>>>(x, tem, xin_tm);

  // Q, K: C[m][o] = xin[m][:] . W[o][:]  (token-major out)
  gemm_bt<0><<<dim3(4, 85, B_), 256, 0, stream>>>(xin_tm, 512, sBNT,
                                                  wqb, 512, (size_t)0,
                                                  q_tm, 512, sBNT, bq, 512);
  gemm_bt<0><<<dim3(4, 85, B_), 256, 0, stream>>>(xin_tm, 512, sBNT,
                                                  wkb, 512, (size_t)0,
                                                  k_tm, 512, sBNT, bk, 512);
  // V: C[o][m] (channel-major out)
  gemm_bt<1><<<dim3(85, 4, B_), 256, 0, stream>>>(wvb, 512, (size_t)0,
                                                  xin_tm, 512, sBNT,
                                                  v_cm, NT_, sBNT, bv, 512);
  attn<<<dim3(N_, KH_, B_), 256, 0, stream>>>(q_tm, k_tm, v_cm, ao_tm);

  // Y = relu(Wo . ao + bo), fp32 channel-major straight to d_out
  gemm_bt<2><<<dim3(85, 4, B_), 256, 0, stream>>>(wob, 512, (size_t)0,
                                                  ao_tm, 512, sBNT,
                                                  out, NT_, sBNT, bo, 512);
}